// Round 3
// baseline (184.033 us; speedup 1.0000x reference)
//
#include <hip/hip_runtime.h>
#include <math.h>

// ---------------- static problem structure (LMAX=4, taus=16) ----------------
#define NTRI 42
#define NCH  10752
#define B_SZ 256

// runtime copies for k_init (runtime-indexed)
__constant__ int TL[NTRI]  = {0,0,0,0,0, 1,1,1,1,1,1,1,1, 2,2,2,2,2,2,2,2,2,2, 3,3,3,3,3,3,3,3,3,3, 4,4,4,4,4,4,4,4,4};
__constant__ int TL1[NTRI] = {0,1,2,3,4, 1,1,2,2,3,3,4,4, 1,2,2,2,3,3,3,4,4,4, 2,2,3,3,3,3,4,4,4,4, 2,3,3,3,4,4,4,4,4};
__constant__ int TL2[NTRI] = {0,1,2,3,4, 0,1,1,2,2,3,3,4, 1,0,1,2,1,2,3,2,3,4, 1,2,0,1,2,3,1,2,3,4, 2,1,2,3,0,1,2,3,4};

// compile-time copies for templates (same data, sorted by (l,l1,l2))
constexpr int CT_L [NTRI]={0,0,0,0,0, 1,1,1,1,1,1,1,1, 2,2,2,2,2,2,2,2,2,2, 3,3,3,3,3,3,3,3,3,3, 4,4,4,4,4,4,4,4,4};
constexpr int CT_L1[NTRI]={0,1,2,3,4, 1,1,2,2,3,3,4,4, 1,2,2,2,3,3,3,4,4,4, 2,2,3,3,3,3,4,4,4,4, 2,3,3,3,4,4,4,4,4};
constexpr int CT_L2[NTRI]={0,1,2,3,4, 0,1,1,2,2,3,3,4, 1,0,1,2,1,2,3,2,3,4, 1,2,0,1,2,3,1,2,3,4, 2,1,2,3,0,1,2,3,4};
constexpr int CT_T [NTRI]={0,1,2,3,4, 0,1,2,3,4,5,6,7, 0,1,2,3,4,5,6,7,8,9, 0,1,2,3,4,5,6,7,8,9, 0,1,2,3,4,5,6,7,8};

constexpr int KL_t[5]    ={1280,2048,2560,2560,2304};   // t_FF[l]
constexpr int GBASE_t[5] ={0,1280,3328,5888,8448};      // channel base
constexpr int ROFF_t[5]  ={0,16,64,144,256};            // row offset in 400-row layout
constexpr int WOFF_t[5]  ={0,20480,53248,94208,135168}; // complex offset into W
constexpr int NT_L[5]    ={5,8,10,10,9};                // tiles (=triples) per l
constexpr int TRIBASE[5] ={0,5,13,23,33};               // first triple index of each l

// ---------------- device globals ----------------
__device__ float g_varsum[NCH];
__device__ float g_cgcD[NTRI][81];   // dense CG: slot = mi*n1 + p  (0 if invalid)

// ---------------- CG coefficient (exact reference formula, fp64) ----------------
__device__ double dfact(int n){ double r=1.0; for(int i=2;i<=n;i++) r*=(double)i; return r; }

__device__ double cg_coef(int j1,int m1,int j2,int m2,int j,int m){
    if (m1+m2!=m) return 0.0;
    double pref = sqrt((2.0*j+1.0)*dfact(j+j1-j2)*dfact(j-j1+j2)*dfact(j1+j2-j)/dfact(j1+j2+j+1));
    pref *= sqrt(dfact(j+m)*dfact(j-m)*dfact(j1-m1)*dfact(j1+m1)*dfact(j2-m2)*dfact(j2+m2));
    double s=0.0;
    for(int k=0;k<=j1+j2-j;k++){
        int a=j1-m1-k, bb=j2+m2-k, c=j-j2+m1+k, d=j-j1-m2+k;
        if(a<0||bb<0||c<0||d<0) continue;
        double term = 1.0/(dfact(k)*dfact(j1+j2-j-k)*dfact(a)*dfact(bb)*dfact(c)*dfact(d));
        s += (k&1)? -term : term;
    }
    return pref*s;
}

// ---------------- kernel 1: init — zero varsum + build dense CG tables --------
__global__ void k_init(){
    const int tr = blockIdx.x, t = threadIdx.x;
    for(int i = blockIdx.x*blockDim.x + t; i < NCH; i += gridDim.x*blockDim.x)
        g_varsum[i] = 0.f;
    const int l=TL[tr], l1=TL1[tr], l2=TL2[tr];
    const int nm=2*l+1, n1=2*l1+1;
    if(t < nm*n1){
        const int mi = t / n1, p = t % n1;
        const int m = mi - l, m1 = p - l1, m2 = m - m1;
        float c = 0.f;
        if(m2 >= -l2 && m2 <= l2) c = (float)cg_coef(l1,m1,l2,m2,l,m);
        g_cgcD[tr][t] = c;
    }
}

// ---------------- CG product in registers: thread = pair (i,j) ----------------
// ff[mi] = sum_p cg[mi*n1+p] * (A[i][p] * B[j][q]),  q = mi - L - p + L1 + L2
template<int L,int L1,int L2>
__device__ __forceinline__ void cg_compute(const float2* __restrict__ FsB,
                                           const float* __restrict__ cg,
                                           int i, int j, float2 (&ff)[2*L+1]){
    constexpr int N1=2*L1+1, N2=2*L2+1, NM=2*L+1;
    float2 A[N1], Bv[N2];
    #pragma unroll
    for(int p=0;p<N1;p++) A[p]=FsB[ROFF_t[L1]+i*N1+p];
    #pragma unroll
    for(int q=0;q<N2;q++) Bv[q]=FsB[ROFF_t[L2]+j*N2+q];
    #pragma unroll
    for(int mi=0;mi<NM;mi++){
        float aR=0.f, aI=0.f;
        const int pLo = (mi-L+L1-L2) > 0 ? (mi-L+L1-L2) : 0;
        const int pHi = (mi-L+L1+L2) < 2*L1 ? (mi-L+L1+L2) : 2*L1;
        #pragma unroll
        for(int p=0;p<N1;p++){
            if(p>=pLo && p<=pHi){               // folds at compile time (mi unrolled)
                const float c = cg[mi*N1+p];
                const int q = mi - L - p + L1 + L2;
                const float2 a=A[p], b=Bv[q];
                aR = fmaf(c, a.x*b.x - a.y*b.y, aR);
                aI = fmaf(c, a.x*b.y + a.y*b.x, aI);
            }
        }
        ff[mi]=make_float2(aR,aI);
    }
}

// ---------------- kernel 2: variance pass (no FF materialization) -------------
template<int TR>
__device__ __forceinline__ void var_one(const float2* FsB, int t){
    constexpr int L=CT_L[TR], L1=CT_L1[TR], L2=CT_L2[TR];
    constexpr int NM=2*L+1;
    float2 ff[NM];
    cg_compute<L,L1,L2>(FsB, g_cgcD[TR], t>>4, t&15, ff);
    float n2=0.f;
    #pragma unroll
    for(int m=0;m<NM;m++){ n2=fmaf(ff[m].x,ff[m].x,n2); n2=fmaf(ff[m].y,ff[m].y,n2); }
    atomicAdd(&g_varsum[GBASE_t[L] + CT_T[TR]*256 + t], n2);
}

template<int TR>
__device__ __forceinline__ void var_disp(int tr, const float2* FsB, int t){
    if constexpr (TR < NTRI){
        if(tr==TR) var_one<TR>(FsB,t);
        else       var_disp<TR+1>(tr,FsB,t);
    }
}

__global__ void __launch_bounds__(256) k_var(const float2* __restrict__ Fs){
    var_disp<0>(blockIdx.x, Fs + blockIdx.y*400, threadIdx.x);
}

// ---------------- kernel 3: fused CG-recompute + BN + complex matmul ----------
// block = (l, b), 256 threads. Per tile (=one triple, 256 channels):
//   phase A: thread=(i,j) recomputes ff, scales by 1/(sqrt(var)+eps), stages to LDS
//   phase B: thread=(og=t>>6 -> 4 o's, sub=t&63); 4 outputs share each x-read
template<int L,int L1,int L2,int T>
__device__ __forceinline__ void process_tile(const float2* __restrict__ FsB,
                                             const float2* __restrict__ Wl,
                                             float2* __restrict__ sh,
                                             float2 (&acc)[2*L+1][4], int t){
    constexpr int NM=2*L+1, K=KL_t[L];
    float2 ff[NM];
    cg_compute<L,L1,L2>(FsB, g_cgcD[TRIBASE[L]+T], t>>4, t&15, ff);
    const float v = g_varsum[GBASE_t[L] + T*256 + t] * (1.0f/(256.0f*(float)NM));
    const float invv = 1.0f/(sqrtf(v)+1e-5f);
    __syncthreads();                    // previous tile's phase-B reads done
    #pragma unroll
    for(int m=0;m<NM;m++) sh[m*256+t]=make_float2(ff[m].x*invv, ff[m].y*invv);
    __syncthreads();
    const int og=t>>6, sub=t&63;
    #pragma unroll
    for(int kk=0;kk<4;kk++){
        const int c2 = sub + (kk<<6);
        const int cW = T*256 + c2;
        float2 w[4];
        #pragma unroll
        for(int oo=0;oo<4;oo++) w[oo]=Wl[(4*og+oo)*K + cW];
        #pragma unroll
        for(int m=0;m<NM;m++){
            const float2 x=sh[m*256+c2];
            #pragma unroll
            for(int oo=0;oo<4;oo++){
                acc[m][oo].x = fmaf(w[oo].x,x.x, fmaf(-w[oo].y,x.y, acc[m][oo].x));
                acc[m][oo].y = fmaf(w[oo].x,x.y, fmaf( w[oo].y,x.x, acc[m][oo].y));
            }
        }
    }
}

template<int L,int T>
__device__ __forceinline__ void tiles_loop(const float2* FsB, const float2* Wl,
                                           float2* sh, float2 (&acc)[2*L+1][4], int t){
    if constexpr (T < NT_L[L]){
        process_tile<L, CT_L1[TRIBASE[L]+T], CT_L2[TRIBASE[L]+T], T>(FsB,Wl,sh,acc,t);
        tiles_loop<L,T+1>(FsB,Wl,sh,acc,t);
    }
}

template<int L>
__device__ __forceinline__ void mm_body(const float2* __restrict__ Fs,
                                        const float2* __restrict__ W2,
                                        float2* __restrict__ out,
                                        float2* sh, int b, int t){
    constexpr int NM=2*L+1;
    float2 acc[NM][4];
    #pragma unroll
    for(int m=0;m<NM;m++)
        #pragma unroll
        for(int oo=0;oo<4;oo++) acc[m][oo]=make_float2(0.f,0.f);

    tiles_loop<L,0>(Fs + b*400, W2 + WOFF_t[L], sh, acc, t);

    // wave-level all-reduce over the 64 sub-partials (og == wave id)
    #pragma unroll
    for(int m=0;m<NM;m++)
        #pragma unroll
        for(int oo=0;oo<4;oo++){
            float2 v=acc[m][oo];
            #pragma unroll
            for(int s=1;s<64;s<<=1){
                v.x += __shfl_xor(v.x,s,64);
                v.y += __shfl_xor(v.y,s,64);
            }
            acc[m][oo]=v;
        }
    const int og=t>>6, lane=t&63;
    float2 vout=make_float2(0.f,0.f);
    #pragma unroll
    for(int oo=0;oo<4;oo++)
        #pragma unroll
        for(int m=0;m<NM;m++)
            if(lane==oo*NM+m) vout=acc[m][oo];
    if(lane < 4*NM)
        out[b*400 + ROFF_t[L] + (4*og)*NM + lane] = vout;   // = RO + o*NM + m
}

__global__ void __launch_bounds__(256) k_mm(const float2* __restrict__ Fs,
                                            const float2* __restrict__ W2,
                                            float2* __restrict__ out){
    __shared__ float2 sh[9*256];
    const int b=blockIdx.y, t=threadIdx.x;
    switch(blockIdx.x){
        case 0: mm_body<0>(Fs,W2,out,sh,b,t); break;
        case 1: mm_body<1>(Fs,W2,out,sh,b,t); break;
        case 2: mm_body<2>(Fs,W2,out,sh,b,t); break;
        case 3: mm_body<3>(Fs,W2,out,sh,b,t); break;
        case 4: mm_body<4>(Fs,W2,out,sh,b,t); break;
    }
}

// ---------------- launcher ----------------
extern "C" void kernel_launch(void* const* d_in, const int* in_sizes, int n_in,
                              void* d_out, int out_size, void* d_ws, size_t ws_size,
                              hipStream_t stream){
    const float2* Fs = (const float2*)d_in[0];   // [256,400,2] fp32
    const float2* W  = (const float2*)d_in[1];   // [172032,2]  fp32
    float2* out = (float2*)d_out;                // [256,400,2] fp32

    k_init<<<dim3(NTRI),128,0,stream>>>();
    k_var <<<dim3(NTRI,B_SZ),256,0,stream>>>(Fs);
    k_mm  <<<dim3(5,B_SZ),256,0,stream>>>(Fs,W,out);
}

// Round 4
// 169.459 us; speedup vs baseline: 1.0860x; 1.0860x over previous
//
#include <hip/hip_runtime.h>
#include <math.h>

// ---------------- static problem structure (LMAX=4, taus=16) ----------------
#define NTRI 42
#define NCH  10752
#define B_SZ 256
#define FF_TOT 15073280

// runtime copies (for k_init)
__constant__ int TL[NTRI]  = {0,0,0,0,0, 1,1,1,1,1,1,1,1, 2,2,2,2,2,2,2,2,2,2, 3,3,3,3,3,3,3,3,3,3, 4,4,4,4,4,4,4,4,4};
__constant__ int TL1[NTRI] = {0,1,2,3,4, 1,1,2,2,3,3,4,4, 1,2,2,2,3,3,3,4,4,4, 2,2,3,3,3,3,4,4,4,4, 2,3,3,3,4,4,4,4,4};
__constant__ int TL2[NTRI] = {0,1,2,3,4, 0,1,1,2,2,3,3,4, 1,0,1,2,1,2,3,2,3,4, 1,2,0,1,2,3,1,2,3,4, 2,1,2,3,0,1,2,3,4};

// compile-time copies (sorted by (l,l1,l2))
constexpr int CT_L [NTRI]={0,0,0,0,0, 1,1,1,1,1,1,1,1, 2,2,2,2,2,2,2,2,2,2, 3,3,3,3,3,3,3,3,3,3, 4,4,4,4,4,4,4,4,4};
constexpr int CT_L1[NTRI]={0,1,2,3,4, 1,1,2,2,3,3,4,4, 1,2,2,2,3,3,3,4,4,4, 2,2,3,3,3,3,4,4,4,4, 2,3,3,3,4,4,4,4,4};
constexpr int CT_L2[NTRI]={0,1,2,3,4, 0,1,1,2,2,3,3,4, 1,0,1,2,1,2,3,2,3,4, 1,2,0,1,2,3,1,2,3,4, 2,1,2,3,0,1,2,3,4};
constexpr int CT_T [NTRI]={0,1,2,3,4, 0,1,2,3,4,5,6,7, 0,1,2,3,4,5,6,7,8,9, 0,1,2,3,4,5,6,7,8,9, 0,1,2,3,4,5,6,7,8};

constexpr int KL_t[5]    ={1280,2048,2560,2560,2304};   // t_FF[l]
constexpr int GBASE_t[5] ={0,1280,3328,5888,8448};      // channel base
constexpr int FFBASE_t[5]={0,327680,1900544,5177344,9764864}; // FF complex base
constexpr int ROFF_t[5]  ={0,16,64,144,256};            // row offset in 400-row layout
constexpr int WOFF_t[5]  ={0,20480,53248,94208,135168}; // complex offset into W

// ---------------- device globals ----------------
__device__ float2 g_FF[FF_TOT];      // 120.6 MB intermediate (fp32 complex)
__device__ float  g_varsum[NCH];
__device__ float  g_inv[NCH];
__device__ float  g_cgcD[NTRI][81];  // dense CG: slot = mi*n1 + p (0 if invalid)

// ---------------- CG coefficient via factorial table (fp64) ----------------
__device__ double cg_coefT(const double* F, int j1,int m1,int j2,int m2,int j,int m){
    if(m1+m2!=m) return 0.0;
    double pref = sqrt((2.0*j+1.0)*F[j+j1-j2]*F[j-j1+j2]*F[j1+j2-j]/F[j1+j2+j+1]);
    pref *= sqrt(F[j+m]*F[j-m]*F[j1-m1]*F[j1+m1]*F[j2-m2]*F[j2+m2]);
    double s=0.0;
    for(int k=0;k<=j1+j2-j;k++){
        int a=j1-m1-k, bb=j2+m2-k, c=j-j2+m1+k, d=j-j1-m2+k;
        if(a<0||bb<0||c<0||d<0) continue;
        double term = 1.0/(F[k]*F[j1+j2-j-k]*F[a]*F[bb]*F[c]*F[d]);
        s += (k&1)? -term : term;
    }
    return pref*s;
}

// ---------------- kernel 1: init — zero varsum + dense CG tables --------------
__global__ void k_init(){
    __shared__ double fact[20];
    const int tr=blockIdx.x, t=threadIdx.x;
    if(t==0){ double r=1.0; fact[0]=1.0; for(int i=1;i<20;i++){ r*=(double)i; fact[i]=r; } }
    for(int i=blockIdx.x*blockDim.x+t; i<NCH; i+=gridDim.x*blockDim.x) g_varsum[i]=0.f;
    __syncthreads();
    const int l=TL[tr], l1=TL1[tr], l2=TL2[tr];
    const int nm=2*l+1, n1=2*l1+1;
    if(t < nm*n1){
        const int mi=t/n1, p=t%n1;
        const int m=mi-l, m1=p-l1, m2=m-m1;
        float c=0.f;
        if(m2>=-l2 && m2<=l2) c=(float)cg_coefT(fact,l1,m1,l2,m2,l,m);
        g_cgcD[tr][t]=c;
    }
}

// ---------------- CG product in registers: thread = pair (i,j) ----------------
template<int L,int L1,int L2>
__device__ __forceinline__ void cg_compute(const float2* __restrict__ FsB,
                                           const float* __restrict__ cg,
                                           int i, int j, float2 (&ff)[2*L+1]){
    constexpr int N1=2*L1+1, N2=2*L2+1, NM=2*L+1;
    float2 A[N1], Bv[N2];
    #pragma unroll
    for(int p=0;p<N1;p++) A[p]=FsB[ROFF_t[L1]+i*N1+p];
    #pragma unroll
    for(int q=0;q<N2;q++) Bv[q]=FsB[ROFF_t[L2]+j*N2+q];
    #pragma unroll
    for(int mi=0;mi<NM;mi++){
        float aR=0.f, aI=0.f;
        const int pLo = (mi-L+L1-L2) > 0 ? (mi-L+L1-L2) : 0;
        const int pHi = (mi-L+L1+L2) < 2*L1 ? (mi-L+L1+L2) : 2*L1;
        #pragma unroll
        for(int p=0;p<N1;p++){
            if(p>=pLo && p<=pHi){               // folds at compile time
                const float c = cg[mi*N1+p];
                const int q = mi - L - p + L1 + L2;
                const float2 a=A[p], b=Bv[q];
                aR = fmaf(c, a.x*b.x - a.y*b.y, aR);
                aI = fmaf(c, a.x*b.y + a.y*b.x, aI);
            }
        }
        ff[mi]=make_float2(aR,aI);
    }
}

// ---------------- kernel 2: CG -> FF (materialized) + variance sums -----------
template<int TR>
__device__ __forceinline__ void cg_one(const float2* FsB, int b, int t){
    constexpr int L=CT_L[TR], L1=CT_L1[TR], L2=CT_L2[TR];
    constexpr int NM=2*L+1, K=KL_t[L];
    float2 ff[NM];
    cg_compute<L,L1,L2>(FsB, g_cgcD[TR], t>>4, t&15, ff);
    const int chan = CT_T[TR]*256 + t;
    const int ffb  = FFBASE_t[L] + (b*NM)*K + chan;
    float n2=0.f;
    #pragma unroll
    for(int m=0;m<NM;m++){
        g_FF[ffb + m*K] = ff[m];
        n2 = fmaf(ff[m].x,ff[m].x,n2);
        n2 = fmaf(ff[m].y,ff[m].y,n2);
    }
    atomicAdd(&g_varsum[GBASE_t[L]+chan], n2);
}

template<int TR>
__device__ __forceinline__ void cg_disp(int tr, const float2* FsB, int b, int t){
    if constexpr (TR < NTRI){
        if(tr==TR) cg_one<TR>(FsB,b,t);
        else       cg_disp<TR+1>(tr,FsB,b,t);
    }
}

__global__ void __launch_bounds__(256) k_cg(const float2* __restrict__ Fs){
    cg_disp<0>(blockIdx.x, Fs + blockIdx.y*400, blockIdx.y, threadIdx.x);
}

// ---------------- kernel 3: finalize inv scale ----------------
__global__ void k_inv(){
    int c = blockIdx.x*256 + threadIdx.x;
    if(c>=NCH) return;
    int l = (c<1280)?0:(c<3328)?1:(c<5888)?2:(c<8448)?3:4;
    float v = g_varsum[c]/(256.0f*(float)(2*l+1));
    g_inv[c] = 1.0f/(sqrtf(v)+1e-5f);
}

// ---------------- kernel 4: BN + complex matmul, 4-output register blocking ---
// grid (5, 256). 256 threads. Per 256-channel tile:
//   stage: thread t loads FF[m][c0+t], scales by invv, -> LDS
//   mm:    thread (og=t>>6, sub=t&63): 4 o's share each x-read
template<int L>
__device__ __forceinline__ void mm_body(const float2* __restrict__ W2,
                                        float2* __restrict__ out,
                                        float2* sh, int b, int t){
    constexpr int NM=2*L+1, K=KL_t[L], NT=K/256;
    const float2* Wl = W2 + WOFF_t[L];
    float2 acc[NM][4];
    #pragma unroll
    for(int m=0;m<NM;m++)
        #pragma unroll
        for(int oo=0;oo<4;oo++) acc[m][oo]=make_float2(0.f,0.f);

    const int og=t>>6, sub=t&63;
    for(int T=0;T<NT;T++){
        const int c0=T*256;
        const float invv = g_inv[GBASE_t[L] + c0 + t];
        __syncthreads();                 // previous tile's reads done
        #pragma unroll
        for(int m=0;m<NM;m++){
            float2 v = g_FF[FFBASE_t[L] + (b*NM+m)*K + c0 + t];
            sh[m*256+t] = make_float2(v.x*invv, v.y*invv);
        }
        __syncthreads();
        #pragma unroll
        for(int kk=0;kk<4;kk++){
            const int c2 = sub + (kk<<6);
            float2 w[4];
            #pragma unroll
            for(int oo=0;oo<4;oo++) w[oo]=Wl[(4*og+oo)*K + c0 + c2];
            #pragma unroll
            for(int m=0;m<NM;m++){
                const float2 x=sh[m*256+c2];
                #pragma unroll
                for(int oo=0;oo<4;oo++){
                    acc[m][oo].x = fmaf(w[oo].x,x.x, fmaf(-w[oo].y,x.y, acc[m][oo].x));
                    acc[m][oo].y = fmaf(w[oo].x,x.y, fmaf( w[oo].y,x.x, acc[m][oo].y));
                }
            }
        }
    }

    // wave-level all-reduce over the 64 sub-partials (og == wave id)
    #pragma unroll
    for(int m=0;m<NM;m++)
        #pragma unroll
        for(int oo=0;oo<4;oo++){
            float2 v=acc[m][oo];
            #pragma unroll
            for(int s=1;s<64;s<<=1){
                v.x += __shfl_xor(v.x,s,64);
                v.y += __shfl_xor(v.y,s,64);
            }
            acc[m][oo]=v;
        }
    const int lane=t&63;
    float2 vout=make_float2(0.f,0.f);
    #pragma unroll
    for(int oo=0;oo<4;oo++)
        #pragma unroll
        for(int m=0;m<NM;m++)
            if(lane==oo*NM+m) vout=acc[m][oo];
    if(lane < 4*NM)
        out[b*400 + ROFF_t[L] + (4*og)*NM + lane] = vout;   // = RO + o*NM + m
}

__global__ void __launch_bounds__(256) k_mm(const float2* __restrict__ W2,
                                            float2* __restrict__ out){
    __shared__ float2 sh[9*256];
    const int b=blockIdx.y, t=threadIdx.x;
    switch(blockIdx.x){
        case 0: mm_body<0>(W2,out,sh,b,t); break;
        case 1: mm_body<1>(W2,out,sh,b,t); break;
        case 2: mm_body<2>(W2,out,sh,b,t); break;
        case 3: mm_body<3>(W2,out,sh,b,t); break;
        case 4: mm_body<4>(W2,out,sh,b,t); break;
    }
}

// ---------------- launcher ----------------
extern "C" void kernel_launch(void* const* d_in, const int* in_sizes, int n_in,
                              void* d_out, int out_size, void* d_ws, size_t ws_size,
                              hipStream_t stream){
    const float2* Fs = (const float2*)d_in[0];   // [256,400,2] fp32
    const float2* W  = (const float2*)d_in[1];   // [172032,2]  fp32
    float2* out = (float2*)d_out;                // [256,400,2] fp32

    k_init<<<dim3(NTRI),128,0,stream>>>();
    k_cg  <<<dim3(NTRI,B_SZ),256,0,stream>>>(Fs);
    k_inv <<<dim3((NCH+255)/256),256,0,stream>>>();
    k_mm  <<<dim3(5,B_SZ),256,0,stream>>>(W,out);
}